// Round 2
// baseline (2189.643 us; speedup 1.0000x reference)
//
#include <hip/hip_runtime.h>
#include <hip/hip_bf16.h>
#include <cstdint>
#include <cstddef>

typedef __attribute__((ext_vector_type(8))) __bf16 bf16x8;
typedef __attribute__((ext_vector_type(4))) float f32x4;
typedef __attribute__((ext_vector_type(4))) unsigned short us4;

#define GLOAD_LDS16(g, l)                                                        \
    __builtin_amdgcn_global_load_lds(                                            \
        (const __attribute__((address_space(1))) void*)(g),                      \
        (__attribute__((address_space(3))) void*)(l), 16, 0, 0)

static __device__ __forceinline__ unsigned short f2bf(float x) {
    unsigned int u = __builtin_bit_cast(unsigned int, x);
    return (unsigned short)((u + 0x7FFFu + ((u >> 16) & 1u)) >> 16);
}

static __device__ __forceinline__ float gelu_tanh(float x) {
    // jax.nn.gelu default (approximate=True): 0.5x(1+tanh(0.79788456(x+0.044715x^3)))
    float y = 0.7978845608028654f * (x + 0.044715f * x * x * x);
    y = fminf(fmaxf(y, -11.0f), 11.0f);
    float t = __expf(2.0f * y);
    return 0.5f * x * (1.0f + (t - 1.0f) / (t + 1.0f));
}

// ---------------- Router: logits -> softmax -> mask, plus h -> bf16 ----------
__global__ __launch_bounds__(256) void moe_router_kernel(
    const float* __restrict__ h, const float* __restrict__ Wr,
    const float* __restrict__ br, unsigned short* __restrict__ hbf,
    float* __restrict__ mw)
{
    const int lane = threadIdx.x & 63, wave = threadIdx.x >> 6;
    const int n = blockIdx.x * 4 + wave;  // one token per wave
    const float* hr = h + (size_t)n * 1024;
    const int base = lane * 16;

    float xs[16];
#pragma unroll
    for (int q = 0; q < 4; ++q) {
        f32x4 v = *(const f32x4*)(hr + base + q * 4);
        xs[q * 4 + 0] = v[0]; xs[q * 4 + 1] = v[1];
        xs[q * 4 + 2] = v[2]; xs[q * 4 + 3] = v[3];
    }
    float acc[8] = {0.f, 0.f, 0.f, 0.f, 0.f, 0.f, 0.f, 0.f};
#pragma unroll
    for (int j = 0; j < 16; ++j) {
        const float x = xs[j];
        const f32x4 w0 = *(const f32x4*)(Wr + (size_t)(base + j) * 8);
        const f32x4 w1 = *(const f32x4*)(Wr + (size_t)(base + j) * 8 + 4);
        acc[0] += x * w0[0]; acc[1] += x * w0[1]; acc[2] += x * w0[2]; acc[3] += x * w0[3];
        acc[4] += x * w1[0]; acc[5] += x * w1[1]; acc[6] += x * w1[2]; acc[7] += x * w1[3];
    }
#pragma unroll
    for (int q = 0; q < 4; ++q) {
        us4 o;
        o[0] = f2bf(xs[q * 4 + 0]); o[1] = f2bf(xs[q * 4 + 1]);
        o[2] = f2bf(xs[q * 4 + 2]); o[3] = f2bf(xs[q * 4 + 3]);
        *(us4*)(hbf + (size_t)n * 1024 + base + q * 4) = o;
    }
#pragma unroll
    for (int m = 32; m >= 1; m >>= 1)
#pragma unroll
        for (int e = 0; e < 8; ++e) acc[e] += __shfl_xor(acc[e], m, 64);

    if (lane == 0) {
        float l[8]; float mx = -1e30f;
#pragma unroll
        for (int e = 0; e < 8; ++e) { l[e] = acc[e] + br[e]; mx = fmaxf(mx, l[e]); }
        float s = 0.f;
#pragma unroll
        for (int e = 0; e < 8; ++e) { l[e] = __expf(l[e] - mx); s += l[e]; }
        const float inv = 1.0f / s;
#pragma unroll
        for (int e = 0; e < 8; ++e) {
            const float w = l[e] * inv;
            mw[(size_t)n * 8 + e] = (w > 0.05f) ? w : 0.0f;
        }
    }
}

// ---------- Transpose + fp32->bf16 convert (32x32 tiles, per expert z) -------
__global__ __launch_bounds__(256) void moe_tcvt_kernel(
    const float* __restrict__ in, unsigned short* __restrict__ out,
    int ls, size_t in_es, int os, size_t out_es)
{
    __shared__ unsigned short t[32][33];
    const int e = blockIdx.z;
    const int r = threadIdx.x >> 3, c = (threadIdx.x & 7) * 4;
    const float* I = in + (size_t)e * in_es + (size_t)(blockIdx.x * 32 + r) * ls + blockIdx.y * 32 + c;
    f32x4 v = *(const f32x4*)I;
    t[r][c + 0] = f2bf(v[0]); t[r][c + 1] = f2bf(v[1]);
    t[r][c + 2] = f2bf(v[2]); t[r][c + 3] = f2bf(v[3]);
    __syncthreads();
    unsigned short* O = out + (size_t)e * out_es + (size_t)(blockIdx.y * 32 + r) * os + blockIdx.x * 32 + c;
    us4 o;
    o[0] = t[c + 0][r]; o[1] = t[c + 1][r]; o[2] = t[c + 2][r]; o[3] = t[c + 3][r];
    *(us4*)O = o;
}

// ---------------- GEMM1: ghid = mw * gelu(h @ W1 + b1)  (bf16 out) -----------
__global__ __launch_bounds__(256) void moe_gemm1_kernel(
    const unsigned short* __restrict__ A,   // hbf [N][1024]
    const unsigned short* __restrict__ B,   // W1t base (B^T layout, ldb=1024)
    size_t estrideB,                        // per-expert stride in elements
    const float* __restrict__ b1,           // [E][4096]
    const float* __restrict__ mw,           // [N][8]
    unsigned short* __restrict__ Cg,        // ghid [N][E*Fc]
    int Fc, int f0glob)
{
    __shared__ unsigned short Al[128 * 32];
    __shared__ unsigned short Bl[128 * 32];
    __shared__ float s_mw[128];
    const int tid = threadIdx.x, lane = tid & 63, wave = tid >> 6;
    const int m0 = blockIdx.x * 128;
    const int colblk = blockIdx.y * 128;
    const int e = colblk / Fc;              // Fc >= 128 -> tile within one expert
    const int fbase = colblk - e * Fc;
    const unsigned short* Bp = B + (size_t)e * estrideB + (size_t)fbase * 1024;
    if (tid < 128) s_mw[tid] = mw[(size_t)(m0 + tid) * 8 + e];

    f32x4 acc[4][4] = {};
    const int wr = wave >> 1, wc = wave & 1;
    const int aoff = (wr * 64 + (lane & 15)) * 32 + (lane >> 4) * 8;
    const int boff = (wc * 64 + (lane & 15)) * 32 + (lane >> 4) * 8;
    const int r0 = tid >> 2, c80 = (tid & 3) * 8;
    const int r1 = (256 + tid) >> 2, c81 = ((256 + tid) & 3) * 8;
    char* la0 = (char*)Al + (size_t)((wave << 6) * 16);
    char* la1 = (char*)Al + (size_t)((256 + (wave << 6)) * 16);
    char* lb0 = (char*)Bl + (size_t)((wave << 6) * 16);
    char* lb1 = (char*)Bl + (size_t)((256 + (wave << 6)) * 16);

    for (int k0 = 0; k0 < 1024; k0 += 32) {
        GLOAD_LDS16(A + (size_t)(m0 + r0) * 1024 + k0 + c80, la0);
        GLOAD_LDS16(A + (size_t)(m0 + r1) * 1024 + k0 + c81, la1);
        GLOAD_LDS16(Bp + (size_t)r0 * 1024 + k0 + c80, lb0);
        GLOAD_LDS16(Bp + (size_t)r1 * 1024 + k0 + c81, lb1);
        __syncthreads();
        bf16x8 af[4], bq[4];
#pragma unroll
        for (int i = 0; i < 4; ++i) {
            af[i] = *(const bf16x8*)&Al[aoff + i * 512];
            bq[i] = *(const bf16x8*)&Bl[boff + i * 512];
        }
#pragma unroll
        for (int i = 0; i < 4; ++i)
#pragma unroll
            for (int j = 0; j < 4; ++j)
                acc[i][j] = __builtin_amdgcn_mfma_f32_16x16x32_bf16(af[i], bq[j], acc[i][j], 0, 0, 0);
        __syncthreads();
    }

    const int cr = (lane >> 4) * 4;
    const int ccl = lane & 15;
    const size_t ldC = (size_t)Fc * 8;
    const float* b1p = b1 + (size_t)e * 4096 + f0glob + fbase;
#pragma unroll
    for (int i = 0; i < 4; ++i) {
#pragma unroll
        for (int rr = 0; rr < 4; ++rr) {
            const int lr = wr * 64 + i * 16 + cr + rr;
            const float w = s_mw[lr];
            unsigned short* crow = Cg + (size_t)(m0 + lr) * ldC + colblk;
#pragma unroll
            for (int j = 0; j < 4; ++j) {
                const int lc = wc * 64 + j * 16 + ccl;
                const float x = acc[i][j][rr] + b1p[lc];
                crow[lc] = f2bf(w * gelu_tanh(x));
            }
        }
    }
}

// ------------- GEMM2: out (fp32) (+)= ghid @ W2  (accum into d_out) ----------
__global__ __launch_bounds__(256) void moe_gemm2_kernel(
    const unsigned short* __restrict__ A,   // ghid [N][Kc]
    const unsigned short* __restrict__ B,   // W2t base (B^T layout)
    size_t estrideB, int ldb,
    float* __restrict__ Cacc,               // d_out [N][1024] fp32
    int Kc, int logFc, int init)
{
    __shared__ unsigned short Al[128 * 32];
    __shared__ unsigned short Bl[128 * 32];
    const int tid = threadIdx.x, lane = tid & 63, wave = tid >> 6;
    const int m0 = blockIdx.x * 128, n0 = blockIdx.y * 128;

    f32x4 acc[4][4] = {};
    const int wr = wave >> 1, wc = wave & 1;
    const int aoff = (wr * 64 + (lane & 15)) * 32 + (lane >> 4) * 8;
    const int boff = (wc * 64 + (lane & 15)) * 32 + (lane >> 4) * 8;
    const int r0 = tid >> 2, c80 = (tid & 3) * 8;
    const int r1 = (256 + tid) >> 2, c81 = ((256 + tid) & 3) * 8;
    char* la0 = (char*)Al + (size_t)((wave << 6) * 16);
    char* la1 = (char*)Al + (size_t)((256 + (wave << 6)) * 16);
    char* lb0 = (char*)Bl + (size_t)((wave << 6) * 16);
    char* lb1 = (char*)Bl + (size_t)((256 + (wave << 6)) * 16);

    for (int k0 = 0; k0 < Kc; k0 += 32) {
        const int e = k0 >> logFc;
        const int kc0 = k0 - (e << logFc);
        const unsigned short* Bp = B + (size_t)e * estrideB + kc0;
        GLOAD_LDS16(A + (size_t)(m0 + r0) * Kc + k0 + c80, la0);
        GLOAD_LDS16(A + (size_t)(m0 + r1) * Kc + k0 + c81, la1);
        GLOAD_LDS16(Bp + (size_t)(n0 + r0) * ldb + c80, lb0);
        GLOAD_LDS16(Bp + (size_t)(n0 + r1) * ldb + c81, lb1);
        __syncthreads();
        bf16x8 af[4], bq[4];
#pragma unroll
        for (int i = 0; i < 4; ++i) {
            af[i] = *(const bf16x8*)&Al[aoff + i * 512];
            bq[i] = *(const bf16x8*)&Bl[boff + i * 512];
        }
#pragma unroll
        for (int i = 0; i < 4; ++i)
#pragma unroll
            for (int j = 0; j < 4; ++j)
                acc[i][j] = __builtin_amdgcn_mfma_f32_16x16x32_bf16(af[i], bq[j], acc[i][j], 0, 0, 0);
        __syncthreads();
    }

    const int cr = (lane >> 4) * 4;
    const int ccl = lane & 15;
#pragma unroll
    for (int i = 0; i < 4; ++i) {
#pragma unroll
        for (int rr = 0; rr < 4; ++rr) {
            const int lr = wr * 64 + i * 16 + cr + rr;
            float* cp = Cacc + (size_t)(m0 + lr) * 1024 + n0;
#pragma unroll
            for (int j = 0; j < 4; ++j) {
                const int lc = wc * 64 + j * 16 + ccl;
                const float v = acc[i][j][rr];
                if (init) cp[lc] = v; else cp[lc] += v;
            }
        }
    }
}

// ------------- Combine (in-place fp32): out += sum_e mw*b2 -------------------
__global__ __launch_bounds__(256) void moe_combine_kernel(
    float* __restrict__ out, const float* __restrict__ mw,
    const float* __restrict__ b2)
{
    const int n = blockIdx.x, t = threadIdx.x;
    const int d = t * 4;
    f32x4 v = *(const f32x4*)(out + (size_t)n * 1024 + d);
#pragma unroll
    for (int e = 0; e < 8; ++e) {
        const float w = mw[(size_t)n * 8 + e];
        const f32x4 b = *(const f32x4*)(b2 + (size_t)e * 1024 + d);
        v = v + w * b;
    }
    *(f32x4*)(out + (size_t)n * 1024 + d) = v;
}

extern "C" void kernel_launch(void* const* d_in, const int* in_sizes, int n_in,
                              void* d_out, int out_size, void* d_ws, size_t ws_size,
                              hipStream_t stream)
{
    (void)in_sizes; (void)n_in; (void)out_size;
    const float* h  = (const float*)d_in[0];
    const float* Wr = (const float*)d_in[1];
    const float* br = (const float*)d_in[2];
    const float* W1 = (const float*)d_in[3];
    const float* b1 = (const float*)d_in[4];
    const float* W2 = (const float*)d_in[5];
    const float* b2 = (const float*)d_in[6];
    float* out = (float*)d_out;   // fp32 output [N][D]

    const int N = 8192, D = 1024, F = 4096, E = 8;
    auto al = [](size_t x) { return (x + 255) & ~(size_t)255; };
    const size_t sz_hbf = al((size_t)N * D * 2);
    const size_t sz_mw  = al((size_t)N * E * 4);
    auto tot = [&](int fc, bool full) {
        size_t s = sz_hbf + sz_mw + al((size_t)N * E * fc * 2);
        s += (full ? al((size_t)E * F * D * 2) : al((size_t)E * fc * D * 2)) * 2;
        return s;
    };
    int Fc; bool full;
    if      (tot(512, true)  <= ws_size) { Fc = 512; full = true;  }
    else if (tot(512, false) <= ws_size) { Fc = 512; full = false; }
    else if (tot(256, false) <= ws_size) { Fc = 256; full = false; }
    else                                 { Fc = 128; full = false; }
    const int logFc = (Fc == 512) ? 9 : (Fc == 256 ? 8 : 7);

    char* p = (char*)d_ws;
    unsigned short* hbf = (unsigned short*)p; p += sz_hbf;
    float* mwp  = (float*)p; p += sz_mw;
    unsigned short* ghid = (unsigned short*)p; p += al((size_t)N * E * Fc * 2);
    unsigned short* W1t  = (unsigned short*)p;
    p += full ? al((size_t)E * F * D * 2) : al((size_t)E * Fc * D * 2);
    unsigned short* W2t  = (unsigned short*)p;

    moe_router_kernel<<<N / 4, 256, 0, stream>>>(h, Wr, br, hbf, mwp);

    if (full) {
        moe_tcvt_kernel<<<dim3(D / 32, F / 32, E), 256, 0, stream>>>(
            W1, W1t, F, (size_t)D * F, D, (size_t)F * D);
        moe_tcvt_kernel<<<dim3(F / 32, D / 32, E), 256, 0, stream>>>(
            W2, W2t, D, (size_t)F * D, F, (size_t)D * F);
    }

    const int nch = F / Fc;
    for (int c = 0; c < nch; ++c) {
        if (!full) {
            moe_tcvt_kernel<<<dim3(D / 32, Fc / 32, E), 256, 0, stream>>>(
                W1 + (size_t)c * Fc, W1t, F, (size_t)D * F, D, (size_t)Fc * D);
            moe_tcvt_kernel<<<dim3(Fc / 32, D / 32, E), 256, 0, stream>>>(
                W2 + (size_t)c * Fc * D, W2t, D, (size_t)F * D, Fc, (size_t)D * Fc);
        }
        const unsigned short* B1p = W1t + (full ? (size_t)c * Fc * D : 0);
        const size_t es1 = full ? (size_t)F * D : (size_t)Fc * D;
        moe_gemm1_kernel<<<dim3(N / 128, E * Fc / 128), 256, 0, stream>>>(
            hbf, B1p, es1, b1, mwp, ghid, Fc, c * Fc);

        const unsigned short* B2p = W2t + (full ? (size_t)c * Fc : 0);
        const size_t es2 = full ? (size_t)D * F : (size_t)D * Fc;
        const int ldb2 = full ? F : Fc;
        moe_gemm2_kernel<<<dim3(N / 128, D / 128), 256, 0, stream>>>(
            ghid, B2p, es2, ldb2, out, E * Fc, logFc, (c == 0) ? 1 : 0);
    }

    moe_combine_kernel<<<N, 256, 0, stream>>>(out, mwp, b2);
}

// Round 3
// 2059.579 us; speedup vs baseline: 1.0632x; 1.0632x over previous
//
#include <hip/hip_runtime.h>
#include <hip/hip_bf16.h>
#include <cstdint>
#include <cstddef>

typedef __attribute__((ext_vector_type(8))) __bf16 bf16x8;
typedef __attribute__((ext_vector_type(4))) float f32x4;
typedef __attribute__((ext_vector_type(4))) unsigned short us4;

#define GLOAD_LDS16(g, l)                                                        \
    __builtin_amdgcn_global_load_lds(                                            \
        (const __attribute__((address_space(1))) void*)(g),                      \
        (__attribute__((address_space(3))) void*)(l), 16, 0, 0)

static __device__ __forceinline__ unsigned short f2bf(float x) {
    unsigned int u = __builtin_bit_cast(unsigned int, x);
    return (unsigned short)((u + 0x7FFFu + ((u >> 16) & 1u)) >> 16);
}

// gelu(x) = x * sigmoid(1.5957691x + 0.0713548x^3)  (== tanh-form gelu)
static __device__ __forceinline__ float gelu_fast(float x) {
    const float p = x * x;
    const float u = x * fmaf(0.0713548162726f, p, 1.59576912161f);
    const float t = __expf(-u);
    return x * __builtin_amdgcn_rcpf(1.0f + t);
}

// ---------------- Router: logits -> softmax -> mask, plus h -> bf16 ----------
__global__ __launch_bounds__(256) void moe_router_kernel(
    const float* __restrict__ h, const float* __restrict__ Wr,
    const float* __restrict__ br, unsigned short* __restrict__ hbf,
    float* __restrict__ mw)
{
    const int lane = threadIdx.x & 63, wave = threadIdx.x >> 6;
    const int n = blockIdx.x * 4 + wave;  // one token per wave
    const float* hr = h + (size_t)n * 1024;
    const int base = lane * 16;

    float xs[16];
#pragma unroll
    for (int q = 0; q < 4; ++q) {
        f32x4 v = *(const f32x4*)(hr + base + q * 4);
        xs[q * 4 + 0] = v[0]; xs[q * 4 + 1] = v[1];
        xs[q * 4 + 2] = v[2]; xs[q * 4 + 3] = v[3];
    }
    float acc[8] = {0.f, 0.f, 0.f, 0.f, 0.f, 0.f, 0.f, 0.f};
#pragma unroll
    for (int j = 0; j < 16; ++j) {
        const float x = xs[j];
        const f32x4 w0 = *(const f32x4*)(Wr + (size_t)(base + j) * 8);
        const f32x4 w1 = *(const f32x4*)(Wr + (size_t)(base + j) * 8 + 4);
        acc[0] += x * w0[0]; acc[1] += x * w0[1]; acc[2] += x * w0[2]; acc[3] += x * w0[3];
        acc[4] += x * w1[0]; acc[5] += x * w1[1]; acc[6] += x * w1[2]; acc[7] += x * w1[3];
    }
#pragma unroll
    for (int q = 0; q < 4; ++q) {
        us4 o;
        o[0] = f2bf(xs[q * 4 + 0]); o[1] = f2bf(xs[q * 4 + 1]);
        o[2] = f2bf(xs[q * 4 + 2]); o[3] = f2bf(xs[q * 4 + 3]);
        *(us4*)(hbf + (size_t)n * 1024 + base + q * 4) = o;
    }
#pragma unroll
    for (int m = 32; m >= 1; m >>= 1)
#pragma unroll
        for (int e = 0; e < 8; ++e) acc[e] += __shfl_xor(acc[e], m, 64);

    if (lane == 0) {
        float l[8]; float mx = -1e30f;
#pragma unroll
        for (int e = 0; e < 8; ++e) { l[e] = acc[e] + br[e]; mx = fmaxf(mx, l[e]); }
        float s = 0.f;
#pragma unroll
        for (int e = 0; e < 8; ++e) { l[e] = __expf(l[e] - mx); s += l[e]; }
        const float inv = 1.0f / s;
#pragma unroll
        for (int e = 0; e < 8; ++e) {
            const float w = l[e] * inv;
            mw[(size_t)n * 8 + e] = (w > 0.05f) ? w : 0.0f;
        }
    }
}

// ---------- Transpose + fp32->bf16 convert (32x32 tiles, per expert z) -------
__global__ __launch_bounds__(256) void moe_tcvt_kernel(
    const float* __restrict__ in, unsigned short* __restrict__ out,
    int ls, size_t in_es, int os, size_t out_es)
{
    __shared__ unsigned short t[32][33];
    const int e = blockIdx.z;
    const int r = threadIdx.x >> 3, c = (threadIdx.x & 7) * 4;
    const float* I = in + (size_t)e * in_es + (size_t)(blockIdx.x * 32 + r) * ls + blockIdx.y * 32 + c;
    f32x4 v = *(const f32x4*)I;
    t[r][c + 0] = f2bf(v[0]); t[r][c + 1] = f2bf(v[1]);
    t[r][c + 2] = f2bf(v[2]); t[r][c + 3] = f2bf(v[3]);
    __syncthreads();
    unsigned short* O = out + (size_t)e * out_es + (size_t)(blockIdx.y * 32 + r) * os + blockIdx.x * 32 + c;
    us4 o;
    o[0] = t[c + 0][r]; o[1] = t[c + 1][r]; o[2] = t[c + 2][r]; o[3] = t[c + 3][r];
    *(us4*)O = o;
}

// ---------------- GEMM1: ghid = mw * gelu(h @ W1 + b1)  (bf16 out) -----------
// Swapped-operand MFMA: acc[i][j] holds D'[n][m] (reg walks n = F-col).
__global__ __launch_bounds__(256) void moe_gemm1_kernel(
    const unsigned short* __restrict__ A,   // hbf [N][1024]
    const unsigned short* __restrict__ B,   // W1t base (B^T layout, ldb=1024)
    size_t estrideB,
    const float* __restrict__ b1,           // [E][4096]
    const float* __restrict__ mw,           // [N][8]
    unsigned short* __restrict__ Cg,        // ghid [N][E*Fc]
    int Fc, int f0glob)
{
    __shared__ unsigned short Al[128 * 32];
    __shared__ unsigned short Bl[128 * 32];
    __shared__ float s_mw[128];
    const int tid = threadIdx.x, lane = tid & 63, wave = tid >> 6;

    // bijective XCD-chunk swizzle (total % 8 == 0)
    const int gx = gridDim.x, total = gx * gridDim.y;
    const int orig = blockIdx.x + blockIdx.y * gx;
    const int nid = (orig & 7) * (total >> 3) + (orig >> 3);
    const int bx = nid % gx, by = nid / gx;

    const int m0 = bx * 128;
    const int colblk = by * 128;
    const int e = colblk / Fc;              // Fc >= 128 -> tile within one expert
    const int fbase = colblk - e * Fc;
    const unsigned short* Bp = B + (size_t)e * estrideB + (size_t)fbase * 1024;
    if (tid < 128) s_mw[tid] = mw[(size_t)(m0 + tid) * 8 + e];

    f32x4 acc[4][4] = {};
    const int wr = wave >> 1, wc = wave & 1;
    const int aoff = (wr * 64 + (lane & 15)) * 32 + (lane >> 4) * 8;
    const int boff = (wc * 64 + (lane & 15)) * 32 + (lane >> 4) * 8;
    const int r0 = tid >> 2, c80 = (tid & 3) * 8;
    const int r1 = (256 + tid) >> 2, c81 = ((256 + tid) & 3) * 8;
    char* la0 = (char*)Al + (size_t)((wave << 6) * 16);
    char* la1 = (char*)Al + (size_t)((256 + (wave << 6)) * 16);
    char* lb0 = (char*)Bl + (size_t)((wave << 6) * 16);
    char* lb1 = (char*)Bl + (size_t)((256 + (wave << 6)) * 16);

    for (int k0 = 0; k0 < 1024; k0 += 32) {
        GLOAD_LDS16(A + (size_t)(m0 + r0) * 1024 + k0 + c80, la0);
        GLOAD_LDS16(A + (size_t)(m0 + r1) * 1024 + k0 + c81, la1);
        GLOAD_LDS16(Bp + (size_t)r0 * 1024 + k0 + c80, lb0);
        GLOAD_LDS16(Bp + (size_t)r1 * 1024 + k0 + c81, lb1);
        __syncthreads();
        bf16x8 af[4], bq[4];
#pragma unroll
        for (int i = 0; i < 4; ++i) {
            af[i] = *(const bf16x8*)&Al[aoff + i * 512];
            bq[i] = *(const bf16x8*)&Bl[boff + i * 512];
        }
#pragma unroll
        for (int i = 0; i < 4; ++i)
#pragma unroll
            for (int j = 0; j < 4; ++j)
                acc[i][j] = __builtin_amdgcn_mfma_f32_16x16x32_bf16(bq[j], af[i], acc[i][j], 0, 0, 0);
        __syncthreads();
    }

    // Epilogue: lane holds 4 consecutive F-cols (reg) for token = lane&15.
    const int tcol = lane & 15;
    const int nr0 = (lane >> 4) * 4;
    const size_t ldC = (size_t)Fc * 8;
    const float* b1p = b1 + (size_t)e * 4096 + f0glob + fbase;
    f32x4 b1v[4];
#pragma unroll
    for (int j = 0; j < 4; ++j)
        b1v[j] = *(const f32x4*)(b1p + wc * 64 + j * 16 + nr0);
#pragma unroll
    for (int i = 0; i < 4; ++i) {
        const int token = wr * 64 + i * 16 + tcol;
        const float w = s_mw[token];
        unsigned short* crow = Cg + (size_t)(m0 + token) * ldC + colblk;
#pragma unroll
        for (int j = 0; j < 4; ++j) {
            const int n = wc * 64 + j * 16 + nr0;
            us4 o;
#pragma unroll
            for (int r = 0; r < 4; ++r)
                o[r] = f2bf(w * gelu_fast(acc[i][j][r] + b1v[j][r]));
            *(us4*)(crow + n) = o;
        }
    }
}

// ------------- GEMM2: out (fp32) (+)= ghid @ W2  (accum into d_out) ----------
__global__ __launch_bounds__(256) void moe_gemm2_kernel(
    const unsigned short* __restrict__ A,   // ghid [N][Kc]
    const unsigned short* __restrict__ B,   // W2t base (B^T layout)
    size_t estrideB, int ldb,
    float* __restrict__ Cacc,               // d_out [N][1024] fp32
    int Kc, int logFc, int init)
{
    __shared__ unsigned short Al[128 * 32];
    __shared__ unsigned short Bl[128 * 32];
    const int tid = threadIdx.x, lane = tid & 63, wave = tid >> 6;

    const int gx = gridDim.x, total = gx * gridDim.y;
    const int orig = blockIdx.x + blockIdx.y * gx;
    const int nid = (orig & 7) * (total >> 3) + (orig >> 3);
    const int bx = nid % gx, by = nid / gx;
    const int m0 = bx * 128, n0 = by * 128;

    f32x4 acc[4][4] = {};
    const int wr = wave >> 1, wc = wave & 1;
    const int aoff = (wr * 64 + (lane & 15)) * 32 + (lane >> 4) * 8;
    const int boff = (wc * 64 + (lane & 15)) * 32 + (lane >> 4) * 8;
    const int r0 = tid >> 2, c80 = (tid & 3) * 8;
    const int r1 = (256 + tid) >> 2, c81 = ((256 + tid) & 3) * 8;
    char* la0 = (char*)Al + (size_t)((wave << 6) * 16);
    char* la1 = (char*)Al + (size_t)((256 + (wave << 6)) * 16);
    char* lb0 = (char*)Bl + (size_t)((wave << 6) * 16);
    char* lb1 = (char*)Bl + (size_t)((256 + (wave << 6)) * 16);

    for (int k0 = 0; k0 < Kc; k0 += 32) {
        const int e = k0 >> logFc;
        const int kc0 = k0 - (e << logFc);
        const unsigned short* Bp = B + (size_t)e * estrideB + kc0;
        GLOAD_LDS16(A + (size_t)(m0 + r0) * Kc + k0 + c80, la0);
        GLOAD_LDS16(A + (size_t)(m0 + r1) * Kc + k0 + c81, la1);
        GLOAD_LDS16(Bp + (size_t)(n0 + r0) * ldb + c80, lb0);
        GLOAD_LDS16(Bp + (size_t)(n0 + r1) * ldb + c81, lb1);
        __syncthreads();
        bf16x8 af[4], bq[4];
#pragma unroll
        for (int i = 0; i < 4; ++i) {
            af[i] = *(const bf16x8*)&Al[aoff + i * 512];
            bq[i] = *(const bf16x8*)&Bl[boff + i * 512];
        }
#pragma unroll
        for (int i = 0; i < 4; ++i)
#pragma unroll
            for (int j = 0; j < 4; ++j)
                acc[i][j] = __builtin_amdgcn_mfma_f32_16x16x32_bf16(bq[j], af[i], acc[i][j], 0, 0, 0);
        __syncthreads();
    }

    // Epilogue: vector f32x4 accumulate; lane holds 4 consecutive d-cols.
    const int tcol = lane & 15;
    const int nr0 = (lane >> 4) * 4;
#pragma unroll
    for (int i = 0; i < 4; ++i) {
        const int token = wr * 64 + i * 16 + tcol;
        float* cp = Cacc + (size_t)(m0 + token) * 1024 + n0;
#pragma unroll
        for (int j = 0; j < 4; ++j) {
            const int n = wc * 64 + j * 16 + nr0;
            f32x4 v = acc[i][j];
            if (init) {
                *(f32x4*)(cp + n) = v;
            } else {
                f32x4 old = *(const f32x4*)(cp + n);
                *(f32x4*)(cp + n) = old + v;
            }
        }
    }
}

// ------------- Combine (in-place fp32): out += sum_e mw*b2 -------------------
__global__ __launch_bounds__(256) void moe_combine_kernel(
    float* __restrict__ out, const float* __restrict__ mw,
    const float* __restrict__ b2)
{
    const int n = blockIdx.x, t = threadIdx.x;
    const int d = t * 4;
    f32x4 v = *(const f32x4*)(out + (size_t)n * 1024 + d);
#pragma unroll
    for (int e = 0; e < 8; ++e) {
        const float w = mw[(size_t)n * 8 + e];
        const f32x4 b = *(const f32x4*)(b2 + (size_t)e * 1024 + d);
        v = v + w * b;
    }
    *(f32x4*)(out + (size_t)n * 1024 + d) = v;
}

extern "C" void kernel_launch(void* const* d_in, const int* in_sizes, int n_in,
                              void* d_out, int out_size, void* d_ws, size_t ws_size,
                              hipStream_t stream)
{
    (void)in_sizes; (void)n_in; (void)out_size;
    const float* h  = (const float*)d_in[0];
    const float* Wr = (const float*)d_in[1];
    const float* br = (const float*)d_in[2];
    const float* W1 = (const float*)d_in[3];
    const float* b1 = (const float*)d_in[4];
    const float* W2 = (const float*)d_in[5];
    const float* b2 = (const float*)d_in[6];
    float* out = (float*)d_out;   // fp32 output [N][D]

    const int N = 8192, D = 1024, F = 4096, E = 8;
    auto al = [](size_t x) { return (x + 255) & ~(size_t)255; };
    const size_t sz_hbf = al((size_t)N * D * 2);
    const size_t sz_mw  = al((size_t)N * E * 4);
    auto tot = [&](int fc, bool full) {
        size_t s = sz_hbf + sz_mw + al((size_t)N * E * fc * 2);
        s += (full ? al((size_t)E * F * D * 2) : al((size_t)E * fc * D * 2)) * 2;
        return s;
    };
    int Fc; bool full;
    if      (tot(1024, true)  <= ws_size) { Fc = 1024; full = true;  }
    else if (tot(512,  true)  <= ws_size) { Fc = 512;  full = true;  }
    else if (tot(512,  false) <= ws_size) { Fc = 512;  full = false; }
    else if (tot(256,  false) <= ws_size) { Fc = 256;  full = false; }
    else                                  { Fc = 128;  full = false; }
    const int logFc = (Fc == 1024) ? 10 : (Fc == 512) ? 9 : (Fc == 256 ? 8 : 7);

    char* p = (char*)d_ws;
    unsigned short* hbf = (unsigned short*)p; p += sz_hbf;
    float* mwp  = (float*)p; p += sz_mw;
    unsigned short* ghid = (unsigned short*)p; p += al((size_t)N * E * Fc * 2);
    unsigned short* W1t  = (unsigned short*)p;
    p += full ? al((size_t)E * F * D * 2) : al((size_t)E * Fc * D * 2);
    unsigned short* W2t  = (unsigned short*)p;

    moe_router_kernel<<<N / 4, 256, 0, stream>>>(h, Wr, br, hbf, mwp);

    if (full) {
        moe_tcvt_kernel<<<dim3(D / 32, F / 32, E), 256, 0, stream>>>(
            W1, W1t, F, (size_t)D * F, D, (size_t)F * D);
        moe_tcvt_kernel<<<dim3(F / 32, D / 32, E), 256, 0, stream>>>(
            W2, W2t, D, (size_t)F * D, F, (size_t)D * F);
    }

    const int nch = F / Fc;
    for (int c = 0; c < nch; ++c) {
        if (!full) {
            moe_tcvt_kernel<<<dim3(D / 32, Fc / 32, E), 256, 0, stream>>>(
                W1 + (size_t)c * Fc, W1t, F, (size_t)D * F, D, (size_t)Fc * D);
            moe_tcvt_kernel<<<dim3(Fc / 32, D / 32, E), 256, 0, stream>>>(
                W2 + (size_t)c * Fc * D, W2t, D, (size_t)F * D, Fc, (size_t)D * Fc);
        }
        const unsigned short* B1p = W1t + (full ? (size_t)c * Fc * D : 0);
        const size_t es1 = full ? (size_t)F * D : (size_t)Fc * D;
        moe_gemm1_kernel<<<dim3(N / 128, E * Fc / 128), 256, 0, stream>>>(
            hbf, B1p, es1, b1, mwp, ghid, Fc, c * Fc);

        const unsigned short* B2p = W2t + (full ? (size_t)c * Fc : 0);
        const size_t es2 = full ? (size_t)D * F : (size_t)D * Fc;
        const int ldb2 = full ? F : Fc;
        moe_gemm2_kernel<<<dim3(N / 128, D / 128), 256, 0, stream>>>(
            ghid, B2p, es2, ldb2, out, E * Fc, logFc, (c == 0) ? 1 : 0);
    }

    moe_combine_kernel<<<N, 256, 0, stream>>>(out, mwp, b2);
}